// Round 12
// baseline (24.157 us; speedup 1.0000x reference)
//
#include <hip/hip_runtime.h>

// out[b,i,j,c] = sum_d tanh(start[b,c,i,d] + end[b,c,j,d]) * v[d]
// B=2, C=8, L=256, D=128.
//
// tanh(x) = 1 - 2/(e^{2x}+1);  e^{2(s+e)} = Es*Ee, Es=exp2(K*s), K=2*log2(e).
// u-substitution with -2 folded:  W_d = -0.5/v_d,
//   u_d = fma(Es*W_d, Ee, W_d) = -0.5*q_d/v_d   (q_d = EsEe+1)
//   sum_d v_d tanh(..) = sum(v) + sum_d 1/u_d, and per d-quad the four 1/u
//   merge into ONE rcp: [cd*(u0+u1) + ab*(u2+u3)]/(ab*cd).
//
// R12 = R10 skeleton (best: 18.39 us) + PACKED BF16 TILES:
//   each ds_read_b128 now delivers 8 elements -> tile reads/CU halve
//   (1152 -> 512 b128), the biggest LDS-pipe term. Unpack = shift/and
//   (exact, +2 full-rate per quad). R8 proved bf16-tile accuracy
//   (absmax 0.0078 unchanged). Named scalars only (no runtime-indexed
//   arrays -> no scratch); no min-waves clamp (R7 spill lesson).

#define LDIM 256
#define DDIM 128
#define DPADH 136   // ushort row stride 272 B: rows ty+8k start at bank 4*ty+c

__device__ __forceinline__ unsigned bf1(float x) {       // f32 -> bf16 (RNE)
    unsigned u = __float_as_uint(x);
    u += 0x7FFFu + ((u >> 16) & 1u);
    return u >> 16;
}
__device__ __forceinline__ unsigned pack2(float x, float y) {
    return bf1(x) | (bf1(y) << 16);
}
__device__ __forceinline__ float lo16(unsigned u) { return __uint_as_float(u << 16); }
__device__ __forceinline__ float hi16(unsigned u) { return __uint_as_float(u & 0xFFFF0000u); }

__global__ __launch_bounds__(256) void span_tanh_dot_kernel(
    const float* __restrict__ start_h,
    const float* __restrict__ end_h,
    const float* __restrict__ v,
    float* __restrict__ out,
    int C)
{
    __shared__ float pool[4096];                 // park buf (16 KB); s-tile aliases
    __shared__ unsigned short e_t[32][DPADH];    // 8.7 KB (Ee bf16)
    __shared__ float W_s[DDIM];                  // -0.5 / v[d] (f32, exact in loop)
    __shared__ float s_vsum;
    unsigned short (*s_t)[DPADH] = (unsigned short (*)[DPADH])pool;  // 8.7 KB

    const int bc = blockIdx.z;               // b*C + c
    const int i0 = blockIdx.y * 32;
    const int j0 = blockIdx.x * 32;
    const int tx = threadIdx.x;               // 0..7
    const int ty = threadIdx.y;               // 0..7
    const int g  = threadIdx.z;               // 0..3: wave = d-quarter
    const int t  = ty * 8 + tx;               // lane in wave
    const int tid = g * 64 + t;

    const float K = 2.8853900817779268f;      // 2*log2(e)

    const float* sg = start_h + ((size_t)bc * LDIM + i0) * DDIM;
    const float* eg = end_h   + ((size_t)bc * LDIM + j0) * DDIM;

    // W table (f32)
    if (tid < 32) {
        const float4 vv = *(const float4*)(v + 4 * tid);
        float4 w;
        w.x = -0.5f * __builtin_amdgcn_rcpf(vv.x);
        w.y = -0.5f * __builtin_amdgcn_rcpf(vv.y);
        w.z = -0.5f * __builtin_amdgcn_rcpf(vv.z);
        w.w = -0.5f * __builtin_amdgcn_rcpf(vv.w);
        *(float4*)(&W_s[4 * tid]) = w;
    }

    // stage 32x128 bf16 tiles: s_t = bf16(exp2(K*s) * W_d); e_t = bf16(exp2(K*e))
    // 512 8-elem chunks per tensor, 2 per thread. Coalesced f32 reads.
    #pragma unroll
    for (int k = 0; k < 2; ++k) {
        const int idx = tid + k * 256;
        const int r  = idx >> 4;
        const int c8 = (idx & 15) << 3;
        const float4 va = *(const float4*)(v + c8);
        const float4 vb = *(const float4*)(v + c8 + 4);
        const float w0 = -0.5f * __builtin_amdgcn_rcpf(va.x);
        const float w1 = -0.5f * __builtin_amdgcn_rcpf(va.y);
        const float w2 = -0.5f * __builtin_amdgcn_rcpf(va.z);
        const float w3 = -0.5f * __builtin_amdgcn_rcpf(va.w);
        const float w4 = -0.5f * __builtin_amdgcn_rcpf(vb.x);
        const float w5 = -0.5f * __builtin_amdgcn_rcpf(vb.y);
        const float w6 = -0.5f * __builtin_amdgcn_rcpf(vb.z);
        const float w7 = -0.5f * __builtin_amdgcn_rcpf(vb.w);

        float4 a0 = *(const float4*)(sg + r * DDIM + c8);
        float4 a1 = *(const float4*)(sg + r * DDIM + c8 + 4);
        uint4 ps;
        ps.x = pack2(__builtin_amdgcn_exp2f(K * a0.x) * w0,
                     __builtin_amdgcn_exp2f(K * a0.y) * w1);
        ps.y = pack2(__builtin_amdgcn_exp2f(K * a0.z) * w2,
                     __builtin_amdgcn_exp2f(K * a0.w) * w3);
        ps.z = pack2(__builtin_amdgcn_exp2f(K * a1.x) * w4,
                     __builtin_amdgcn_exp2f(K * a1.y) * w5);
        ps.w = pack2(__builtin_amdgcn_exp2f(K * a1.z) * w6,
                     __builtin_amdgcn_exp2f(K * a1.w) * w7);
        *(uint4*)(&s_t[r][c8]) = ps;

        float4 b0 = *(const float4*)(eg + r * DDIM + c8);
        float4 b1 = *(const float4*)(eg + r * DDIM + c8 + 4);
        uint4 pe;
        pe.x = pack2(__builtin_amdgcn_exp2f(K * b0.x),
                     __builtin_amdgcn_exp2f(K * b0.y));
        pe.y = pack2(__builtin_amdgcn_exp2f(K * b0.z),
                     __builtin_amdgcn_exp2f(K * b0.w));
        pe.z = pack2(__builtin_amdgcn_exp2f(K * b1.x),
                     __builtin_amdgcn_exp2f(K * b1.y));
        pe.w = pack2(__builtin_amdgcn_exp2f(K * b1.z),
                     __builtin_amdgcn_exp2f(K * b1.w));
        *(uint4*)(&e_t[r][c8]) = pe;
    }

    // sum(v): wave 0 butterfly -> LDS broadcast
    if (g == 0) {
        float2 vv = *(const float2*)(v + 2 * t);
        float p = vv.x + vv.y;
        #pragma unroll
        for (int off = 1; off < 64; off <<= 1) p += __shfl_xor(p, off);
        if (t == 0) s_vsum = p;
    }
    __syncthreads();

    const int d0 = __builtin_amdgcn_readfirstlane(g) * 32;  // wave-uniform

    float acc00 = 0.f, acc01 = 0.f, acc02 = 0.f, acc03 = 0.f;
    float acc10 = 0.f, acc11 = 0.f, acc12 = 0.f, acc13 = 0.f;
    float acc20 = 0.f, acc21 = 0.f, acc22 = 0.f, acc23 = 0.f;
    float acc30 = 0.f, acc31 = 0.f, acc32 = 0.f, acc33 = 0.f;

#define UNPACK8(U, P)                                                  \
    const float P##0 = lo16((U).x), P##1 = hi16((U).x),                \
                P##2 = lo16((U).y), P##3 = hi16((U).y),                \
                P##4 = lo16((U).z), P##5 = hi16((U).z),                \
                P##6 = lo16((U).w), P##7 = hi16((U).w);

#define QUAD(ACC, A0, A1, A2, A3, B0, B1, B2, B3, WV)                  \
    {                                                                  \
        float uu0 = fmaf(A0, B0, (WV).x);                              \
        float uu1 = fmaf(A1, B1, (WV).y);                              \
        float uu2 = fmaf(A2, B2, (WV).z);                              \
        float uu3 = fmaf(A3, B3, (WV).w);                              \
        float pab = uu0 * uu1, pcd = uu2 * uu3;                        \
        float pn01 = uu0 + uu1;                                        \
        float pn23 = uu2 + uu3;                                        \
        float pN = fmaf(pn01, pcd, pn23 * pab);                        \
        float prr = __builtin_amdgcn_rcpf(pab * pcd);                  \
        ACC = fmaf(pN, prr, ACC);                                      \
    }

    #pragma unroll
    for (int it = 0; it < 4; ++it) {
        const int d = d0 + it * 8;
        const uint4 SU0 = *(const uint4*)(&s_t[ty     ][d]);  // 8 addrs, 32 banks
        const uint4 SU1 = *(const uint4*)(&s_t[ty +  8][d]);
        const uint4 SU2 = *(const uint4*)(&s_t[ty + 16][d]);
        const uint4 SU3 = *(const uint4*)(&s_t[ty + 24][d]);
        const uint4 EU0 = *(const uint4*)(&e_t[tx     ][d]);
        const uint4 EU1 = *(const uint4*)(&e_t[tx +  8][d]);
        const uint4 EU2 = *(const uint4*)(&e_t[tx + 16][d]);
        const uint4 EU3 = *(const uint4*)(&e_t[tx + 24][d]);
        const float4 Wa = *(const float4*)(&W_s[d]);          // broadcast: free
        const float4 Wb = *(const float4*)(&W_s[d + 4]);

        UNPACK8(SU0, sA) UNPACK8(SU1, sB) UNPACK8(SU2, sC) UNPACK8(SU3, sD)
        UNPACK8(EU0, eA) UNPACK8(EU1, eB) UNPACK8(EU2, eC) UNPACK8(EU3, eD)

        QUAD(acc00, sA0,sA1,sA2,sA3, eA0,eA1,eA2,eA3, Wa);
        QUAD(acc00, sA4,sA5,sA6,sA7, eA4,eA5,eA6,eA7, Wb);
        QUAD(acc01, sA0,sA1,sA2,sA3, eB0,eB1,eB2,eB3, Wa);
        QUAD(acc01, sA4,sA5,sA6,sA7, eB4,eB5,eB6,eB7, Wb);
        QUAD(acc02, sA0,sA1,sA2,sA3, eC0,eC1,eC2,eC3, Wa);
        QUAD(acc02, sA4,sA5,sA6,sA7, eC4,eC5,eC6,eC7, Wb);
        QUAD(acc03, sA0,sA1,sA2,sA3, eD0,eD1,eD2,eD3, Wa);
        QUAD(acc03, sA4,sA5,sA6,sA7, eD4,eD5,eD6,eD7, Wb);

        QUAD(acc10, sB0,sB1,sB2,sB3, eA0,eA1,eA2,eA3, Wa);
        QUAD(acc10, sB4,sB5,sB6,sB7, eA4,eA5,eA6,eA7, Wb);
        QUAD(acc11, sB0,sB1,sB2,sB3, eB0,eB1,eB2,eB3, Wa);
        QUAD(acc11, sB4,sB5,sB6,sB7, eB4,eB5,eB6,eB7, Wb);
        QUAD(acc12, sB0,sB1,sB2,sB3, eC0,eC1,eC2,eC3, Wa);
        QUAD(acc12, sB4,sB5,sB6,sB7, eC4,eC5,eC6,eC7, Wb);
        QUAD(acc13, sB0,sB1,sB2,sB3, eD0,eD1,eD2,eD3, Wa);
        QUAD(acc13, sB4,sB5,sB6,sB7, eD4,eD5,eD6,eD7, Wb);

        QUAD(acc20, sC0,sC1,sC2,sC3, eA0,eA1,eA2,eA3, Wa);
        QUAD(acc20, sC4,sC5,sC6,sC7, eA4,eA5,eA6,eA7, Wb);
        QUAD(acc21, sC0,sC1,sC2,sC3, eB0,eB1,eB2,eB3, Wa);
        QUAD(acc21, sC4,sC5,sC6,sC7, eB4,eB5,eB6,eB7, Wb);
        QUAD(acc22, sC0,sC1,sC2,sC3, eC0,eC1,eC2,eC3, Wa);
        QUAD(acc22, sC4,sC5,sC6,sC7, eC4,eC5,eC6,eC7, Wb);
        QUAD(acc23, sC0,sC1,sC2,sC3, eD0,eD1,eD2,eD3, Wa);
        QUAD(acc23, sC4,sC5,sC6,sC7, eD4,eD5,eD6,eD7, Wb);

        QUAD(acc30, sD0,sD1,sD2,sD3, eA0,eA1,eA2,eA3, Wa);
        QUAD(acc30, sD4,sD5,sD6,sD7, eA4,eA5,eA6,eA7, Wb);
        QUAD(acc31, sD0,sD1,sD2,sD3, eB0,eB1,eB2,eB3, Wa);
        QUAD(acc31, sD4,sD5,sD6,sD7, eB4,eB5,eB6,eB7, Wb);
        QUAD(acc32, sD0,sD1,sD2,sD3, eC0,eC1,eC2,eC3, Wa);
        QUAD(acc32, sD4,sD5,sD6,sD7, eC4,eC5,eC6,eC7, Wb);
        QUAD(acc33, sD0,sD1,sD2,sD3, eD0,eD1,eD2,eD3, Wa);
        QUAD(acc33, sD4,sD5,sD6,sD7, eD4,eD5,eD6,eD7, Wb);
    }
#undef QUAD
#undef UNPACK8

    // ---- conflict-free cross-wave d-reduction in pool, lane-stride-1 ----
    __syncthreads();                        // all tile reads done; pool reusable
    float* red = pool;
#define PARK(A, B, ACC) red[(((A) * 4 + (B)) * 4 + g) * 64 + t] = ACC;
    PARK(0,0,acc00) PARK(0,1,acc01) PARK(0,2,acc02) PARK(0,3,acc03)
    PARK(1,0,acc10) PARK(1,1,acc11) PARK(1,2,acc12) PARK(1,3,acc13)
    PARK(2,0,acc20) PARK(2,1,acc21) PARK(2,2,acc22) PARK(2,3,acc23)
    PARK(3,0,acc30) PARK(3,1,acc31) PARK(3,2,acc32) PARK(3,3,acc33)
#undef PARK
    __syncthreads();

    // wave g combines row-group a = g (4 b32 reads per output, stride-1 lanes)
#define COMB(B)                                                    \
    (red[((g * 4 + (B)) * 4 + 0) * 64 + t] +                       \
     red[((g * 4 + (B)) * 4 + 1) * 64 + t] +                       \
     red[((g * 4 + (B)) * 4 + 2) * 64 + t] +                       \
     red[((g * 4 + (B)) * 4 + 3) * 64 + t])
    const float o0 = COMB(0);
    const float o1 = COMB(1);
    const float o2 = COMB(2);
    const float o3 = COMB(3);
#undef COMB

    const int b_ = bc / C;
    const int c_ = bc - b_ * C;
    const float Sv = s_vsum;
    const int i = i0 + ty + 8 * g;
    const size_t rowbase = (((size_t)b_ * LDIM + i) * LDIM) * C + c_;
    out[rowbase + (size_t)(j0 + tx     ) * C] = Sv + o0;
    out[rowbase + (size_t)(j0 + tx +  8) * C] = Sv + o1;
    out[rowbase + (size_t)(j0 + tx + 16) * C] = Sv + o2;
    out[rowbase + (size_t)(j0 + tx + 24) * C] = Sv + o3;
}

extern "C" void kernel_launch(void* const* d_in, const int* in_sizes, int n_in,
                              void* d_out, int out_size, void* d_ws, size_t ws_size,
                              hipStream_t stream) {
    const float* start_h = (const float*)d_in[0];
    const float* end_h   = (const float*)d_in[1];
    const float* v       = (const float*)d_in[2];
    float* out = (float*)d_out;

    const int BC = in_sizes[0] / (LDIM * DDIM);  // B*C = 16
    const int C  = 8;

    dim3 grid(LDIM / 32, LDIM / 32, BC);   // (8, 8, 16) = 1024 blocks, 4/CU
    dim3 block(8, 8, 4);                   // 256 threads; wave g = d-quarter
    span_tanh_dot_kernel<<<grid, block, 0, stream>>>(start_h, end_h, v, out, C);
}